// Round 6
// baseline (62.770 us; speedup 1.0000x reference)
//
#include <hip/hip_runtime.h>
#include <hip/hip_fp16.h>

// BallQLoss: B=2, N=8192, K=16, radius=0.5, L1 norm, mean over (B,N,K).
// v5b: identical to v5 (container died on infra, not kernel). Two kernels,
// zero memsets.
// K1 scan: block = (64-query group) x (j-slice). Slice candidates packed to
// f16x2 pairs into LDS planes once per block (v_cvt_pkrtz); hot loop reads
// 4 pairs per ds_read_b128 at wave-uniform addresses (HW broadcast, no bank
// conflicts); packed f16 distance; hit = sign bit of d2-R^2 merged 2 ops/pair
// into 16-pair mask words; extraction in ascending j (pointnet2 first-K
// semantics). Per-slice first-16 lists (u16) + counts (u8) -> d_ws.
// Block 0 zeroes the ws accumulator + done counter (runs before K2).
// K2 loss: 16 lanes per query (one per k-slot), slot->slice decode, padded
// slots -> slot 0 (first neighbor); L1 gather, block reduce, atomicAdd into
// ws accumulator; last-finisher block writes the mean to d_out.

#define NQ   8192
#define NB   2
#define KNN  16
#define QPB  64
#define WAVES 8
#define GROUPS (NB * NQ / QPB)         // 256
#define NBQ (NB * NQ)                  // 16384

static __device__ __forceinline__ unsigned pkrtz_u(float a, float b) {
    return __builtin_bit_cast(unsigned, __builtin_amdgcn_cvt_pkrtz(a, b));
}
static __device__ __forceinline__ __half2 u_as_h2(unsigned u) {
    return __builtin_bit_cast(__half2, u);
}

template<int JS>
__global__ __launch_bounds__(QPB * WAVES, 8)
void ballq_scan(const float* __restrict__ pc,
                unsigned short* __restrict__ wsIdx,
                unsigned char* __restrict__ wsCnt,
                float* __restrict__ accum,
                unsigned* __restrict__ done)
{
    constexpr int SL  = NQ / JS;       // candidates in this block's slice
    constexpr int SP  = SL / 2;        // packed pairs in slice
    constexpr int CH2 = SP / WAVES;    // pairs per wave

    __shared__ __align__(16) unsigned lx[SP];
    __shared__ __align__(16) unsigned ly[SP];
    __shared__ __align__(16) unsigned lz[SP];
    __shared__ unsigned short s_idx[QPB][WAVES * KNN + 2];  // stride 130
    __shared__ int s_cnt[QPB][WAVES + 1];

    const int tid = threadIdx.x;
    const int q = tid & 63;            // lane = query slot
    const int c = tid >> 6;            // wave = sub-chunk
    const int s = blockIdx.x % JS;     // j slice
    const int g = blockIdx.x / JS;     // query group 0..255
    const int b = g >> 7;
    const int i = (g & 127) * QPB + q;

    if (blockIdx.x == 0 && tid == 0) { *accum = 0.0f; *done = 0u; }

    const float* __restrict__ pcb = pc + (size_t)b * NQ * 3;
    const float2* __restrict__ f2 = (const float2*)pcb;

    // stage this slice's candidate pairs into LDS planes (f16x2)
    const int gp0 = s * SP;
    for (int p = tid; p < SP; p += QPB * WAVES) {
        const int gp = gp0 + p;
        const float2 v0 = f2[3 * gp + 0];   // (x_e, y_e)
        const float2 v1 = f2[3 * gp + 1];   // (z_e, x_o)
        const float2 v2 = f2[3 * gp + 2];   // (y_o, z_o)
        lx[p] = pkrtz_u(v0.x, v1.y);
        ly[p] = pkrtz_u(v0.y, v2.x);
        lz[p] = pkrtz_u(v1.x, v2.y);
    }

    const float qx = pcb[i * 3 + 0];
    const float qy = pcb[i * 3 + 1];
    const float qz = pcb[i * 3 + 2];
    const __half2 qpx = u_as_h2(pkrtz_u(qx, qx));
    const __half2 qpy = u_as_h2(pkrtz_u(qy, qy));
    const __half2 qpz = u_as_h2(pkrtz_u(qz, qz));
    const __half2 r2  = u_as_h2(0x34003400u);   // (0.25, 0.25)

    __syncthreads();

    int cnt = 0;
    const int pb0 = c * CH2;
    // 64 pairs (128 candidates) per extraction round
    for (int r = 0; r < CH2 && cnt < KNN; r += 64) {
        unsigned mw[4];
#pragma unroll
        for (int w = 0; w < 4; ++w) {
            unsigned m = 0u;
#pragma unroll
            for (int g4 = 0; g4 < 4; ++g4) {
                const int pb = pb0 + r + w * 16 + g4 * 4;
                const uint4 X = *(const uint4*)&lx[pb];   // ds_read_b128, broadcast
                const uint4 Y = *(const uint4*)&ly[pb];
                const uint4 Z = *(const uint4*)&lz[pb];
#define BQ_PAIR(xu, yu, zu) { \
    const __half2 dx = __hsub2(qpx, u_as_h2(xu)); \
    const __half2 dy = __hsub2(qpy, u_as_h2(yu)); \
    const __half2 dz = __hsub2(qpz, u_as_h2(zu)); \
    const __half2 d2 = __hfma2(dx, dx, __hfma2(dy, dy, __hmul2(dz, dz))); \
    const unsigned su = __builtin_bit_cast(unsigned, __hsub2(d2, r2)) & 0x80008000u; \
    m = su | (m >> 1); }
                BQ_PAIR(X.x, Y.x, Z.x)
                BQ_PAIR(X.y, Y.y, Z.y)
                BQ_PAIR(X.z, Y.z, Z.z)
                BQ_PAIR(X.w, Y.w, Z.w)
#undef BQ_PAIR
            }
            mw[w] = m;   // bits 0-15: even cands; bits 16-31: odd cands
        }
        if (!(mw[0] | mw[1] | mw[2] | mw[3])) continue;

        unsigned long long ev =
              (unsigned long long)(mw[0] & 0xFFFFu)
            | ((unsigned long long)(mw[1] & 0xFFFFu) << 16)
            | ((unsigned long long)(mw[2] & 0xFFFFu) << 32)
            | ((unsigned long long)(mw[3] & 0xFFFFu) << 48);
        unsigned long long od =
              (unsigned long long)(mw[0] >> 16)
            | ((unsigned long long)(mw[1] >> 16) << 16)
            | ((unsigned long long)(mw[2] >> 16) << 32)
            | ((unsigned long long)(mw[3] >> 16) << 48);

        const int base = s * SL + 2 * (pb0 + r);
        while ((ev | od) && cnt < KNN) {
            const int pe = ev ? __builtin_ctzll(ev) : 127;
            const int po = od ? __builtin_ctzll(od) : 127;
            int j;
            if (pe <= po) { j = base + 2 * pe;     ev &= ev - 1; }
            else          { j = base + 2 * po + 1; od &= od - 1; }
            s_idx[q][c * KNN + cnt] = (unsigned short)j;
            ++cnt;
        }
    }
    s_cnt[q][c] = cnt;
    __syncthreads();

    // intra-block ordered merge: first <=16 over this block's j-slice
    if (c == 0) {
        const int qid = g * QPB + q;   // 0..16383
        unsigned short* __restrict__ rp = wsIdx + ((size_t)s * NBQ + qid) * KNN;
        int outc = 0;
        for (int c2 = 0; c2 < WAVES && outc < KNN; ++c2) {
            const int f = s_cnt[q][c2];
            const int take = f < (KNN - outc) ? f : (KNN - outc);
            for (int t = 0; t < take; ++t)
                rp[outc++] = s_idx[q][c2 * KNN + t];
        }
        wsCnt[qid * 4 + s] = (unsigned char)outc;
    }
}

template<int JS>
__global__ __launch_bounds__(256)
void ballq_loss(const float* __restrict__ flow,
                const unsigned short* __restrict__ wsIdx,
                const unsigned char* __restrict__ wsCnt,
                float* __restrict__ accum,
                unsigned* __restrict__ done,
                float* __restrict__ out,
                int nblocks)
{
    const int tid = blockIdx.x * 256 + threadIdx.x;
    const int qid = tid >> 4;          // one query per 16 lanes
    const int t   = tid & 15;          // k-slot
    const int b   = qid >> 13;
    const int iq  = qid & (NQ - 1);
    const float* __restrict__ flb = flow + (size_t)b * NQ * 3;

    const unsigned cw = *(const unsigned*)(wsCnt + qid * 4);
    const int b0 = cw & 0xFF;
    const int b1 = (JS > 1) ? ((cw >> 8)  & 0xFF) : 0;
    const int b2 = (JS > 2) ? ((cw >> 16) & 0xFF) : 0;
    const int b3 = (JS > 3) ? ((cw >> 24) & 0xFF) : 0;
    const int c1 = b0, c2c = b0 + b1, c3 = b0 + b1 + b2;
    int tot = b0 + b1 + b2 + b3;
    if (tot > KNN) tot = KNN;
    // tot >= 1 always: self is in-ball (exact f16 zero distance)

    const int seff = (t < tot) ? t : 0;   // padded slots -> first neighbor
    const int sl   = (seff >= c1) + (seff >= c2c) + (seff >= c3);
    const int cum  = (sl == 0) ? 0 : (sl == 1) ? c1 : (sl == 2) ? c2c : c3;
    const int j    = wsIdx[((size_t)sl * NBQ + qid) * KNN + (seff - cum)];

    const float fx = flb[iq * 3 + 0];
    const float fy = flb[iq * 3 + 1];
    const float fz = flb[iq * 3 + 2];
    float l = fabsf(fx - flb[j * 3 + 0]) +
              fabsf(fy - flb[j * 3 + 1]) +
              fabsf(fz - flb[j * 3 + 2]);

    for (int o = 32; o > 0; o >>= 1)
        l += __shfl_down(l, o, 64);
    __shared__ float sred[4];
    if ((threadIdx.x & 63) == 0) sred[threadIdx.x >> 6] = l;
    __syncthreads();
    if (threadIdx.x == 0) {
        atomicAdd(accum, sred[0] + sred[1] + sred[2] + sred[3]);
        __threadfence();
        if (atomicAdd(done, 1u) == (unsigned)(nblocks - 1)) {
            // all blocks' accum-adds happened-before their done-adds
            const float total = atomicAdd(accum, 0.0f);   // device-scope read
            out[0] = total * (1.0f / ((float)NB * NQ * KNN));
        }
    }
}

extern "C" void kernel_launch(void* const* d_in, const int* in_sizes, int n_in,
                              void* d_out, int out_size, void* d_ws, size_t ws_size,
                              hipStream_t stream)
{
    (void)in_sizes; (void)n_in; (void)out_size;
    const float* pc   = (const float*)d_in[0];
    const float* flow = (const float*)d_in[1];
    float* out = (float*)d_out;

    const size_t idxB = (size_t)NBQ * KNN * 2;   // 512 KB per slice
    const size_t cntB = (size_t)NBQ * 4;
    const size_t hdr  = 256;                      // accum + done header
    const int JS = (ws_size >= hdr + 4 * idxB + cntB) ? 4
                 : (ws_size >= hdr + 2 * idxB + cntB) ? 2 : 1;

    float*    accum = (float*)d_ws;
    unsigned* done  = (unsigned*)d_ws + 1;
    unsigned short* wsIdx = (unsigned short*)((char*)d_ws + hdr);
    const int nloss = NBQ * 16 / 256;   // 1024

    if (JS == 4) {
        unsigned char* wsCnt = (unsigned char*)d_ws + hdr + 4 * idxB;
        ballq_scan<4><<<GROUPS * 4, QPB * WAVES, 0, stream>>>(pc, wsIdx, wsCnt, accum, done);
        ballq_loss<4><<<nloss, 256, 0, stream>>>(flow, wsIdx, wsCnt, accum, done, out, nloss);
    } else if (JS == 2) {
        unsigned char* wsCnt = (unsigned char*)d_ws + hdr + 2 * idxB;
        ballq_scan<2><<<GROUPS * 2, QPB * WAVES, 0, stream>>>(pc, wsIdx, wsCnt, accum, done);
        ballq_loss<2><<<nloss, 256, 0, stream>>>(flow, wsIdx, wsCnt, accum, done, out, nloss);
    } else {
        unsigned char* wsCnt = (unsigned char*)d_ws + hdr + 1 * idxB;
        ballq_scan<1><<<GROUPS * 1, QPB * WAVES, 0, stream>>>(pc, wsIdx, wsCnt, accum, done);
        ballq_loss<1><<<nloss, 256, 0, stream>>>(flow, wsIdx, wsCnt, accum, done, out, nloss);
    }
}

// Round 11
// 43.169 us; speedup vs baseline: 1.4540x; 1.4540x over previous
//
#include <hip/hip_runtime.h>
#include <hip/hip_fp16.h>

// BallQLoss: B=2, N=8192, K=16, radius=0.5, L1 norm, mean over (B,N,K).
// v6e: byte-identical resubmit of v6d (container flapped again before
// compile; R9's macro-corruption defect is already fixed here — no
// function-like macros anywhere).
// Single fused kernel (scan+merge+loss) + 1-block epilogue.
// Block = one 64-query group (grid 256, 512 thr, 8 waves, ~61 KB LDS).
// Candidates packed to f16x2 pairs in LDS planes, staged in TWO 2048-pair
// phases (24 KB). Wave c scans its 256-pair sub-range per phase; packed
// v_pk f16 distance; hit = sign bit of d2-R^2 merged into four INDEPENDENT
// 16-pair mask chains (ILP at 2 waves/SIMD); extraction in ascending j.
// 16 ordered (phase,wave) lists per query merged first-16 (pointnet2
// semantics), padded with first neighbor; all 512 threads gather flows +
// L1; block partial -> plain store d_ws[bid] (no atomics, no init).
// Epilogue: 1 block sums 256 partials, writes mean. Replay-safe.

#define NQ   8192
#define NB   2
#define KNN  16
#define QPB  64
#define WAVES 8
#define THREADS (QPB * WAVES)          // 512
#define NBQ (NB * NQ)                  // 16384
#define GROUPS (NBQ / QPB)             // 256
#define PH_PAIRS 2048                  // pairs staged per phase (4096 cands)
#define WPP (PH_PAIRS / WAVES)         // 256 pairs per wave per phase
#define IDXROW 260                     // u16/row: 16 lists * 16 + 4 pad

static __device__ __forceinline__ unsigned pkrtz_u(float a, float b) {
    return __builtin_bit_cast(unsigned, __builtin_amdgcn_cvt_pkrtz(a, b));
}
static __device__ __forceinline__ __half2 u_as_h2(unsigned u) {
    return __builtin_bit_cast(__half2, u);
}
// one candidate PAIR: packed f16 distance, sign bits -> mask chain
static __device__ __forceinline__ void bq_pair(unsigned xu, unsigned yu,
                                               unsigned zu, __half2 qpx,
                                               __half2 qpy, __half2 qpz,
                                               __half2 r2, unsigned& mm) {
    const __half2 dx = __hsub2(qpx, u_as_h2(xu));
    const __half2 dy = __hsub2(qpy, u_as_h2(yu));
    const __half2 dz = __hsub2(qpz, u_as_h2(zu));
    const __half2 d2 = __hfma2(dx, dx, __hfma2(dy, dy, __hmul2(dz, dz)));
    const unsigned su =
        __builtin_bit_cast(unsigned, __hsub2(d2, r2)) & 0x80008000u;
    mm = su | (mm >> 1);
}

__global__ __launch_bounds__(THREADS, 2)
void ballq_fused(const float* __restrict__ pc,
                 const float* __restrict__ flow,
                 float* __restrict__ partial)
{
    __shared__ __align__(16) unsigned lx[PH_PAIRS];   // 8 KB each
    __shared__ __align__(16) unsigned ly[PH_PAIRS];
    __shared__ __align__(16) unsigned lz[PH_PAIRS];
    __shared__ unsigned short s_idx[QPB][IDXROW];     // 33.3 KB
    __shared__ unsigned char  s_cnt[QPB][20];
    __shared__ unsigned short s_mrg[QPB][18];
    __shared__ float s_red[WAVES];

    const int tid = threadIdx.x;
    const int q   = tid & 63;          // lane = query slot
    const int c   = tid >> 6;          // wave id
    const int g   = blockIdx.x;        // query group 0..255
    const int b   = g >> 7;
    const int i   = (g & 127) * QPB + q;

    const float* __restrict__ pcb = pc   + (size_t)b * NQ * 3;
    const float* __restrict__ flb = flow + (size_t)b * NQ * 3;
    const float2* __restrict__ f2 = (const float2*)pcb;

    const float qx = pcb[i * 3 + 0];
    const float qy = pcb[i * 3 + 1];
    const float qz = pcb[i * 3 + 2];
    const __half2 qpx = u_as_h2(pkrtz_u(qx, qx));
    const __half2 qpy = u_as_h2(pkrtz_u(qy, qy));
    const __half2 qpz = u_as_h2(pkrtz_u(qz, qz));
    const __half2 r2  = u_as_h2(0x34003400u);   // (0.25, 0.25)

    for (int h = 0; h < 2; ++h) {
        if (h) __syncthreads();        // phase-0 scan done before restage
        // ---- stage phase h: pairs [h*2048, h*2048+2048) -> LDS planes ----
        for (int p = tid; p < PH_PAIRS; p += THREADS) {
            const int gp = h * PH_PAIRS + p;
            const float2 v0 = f2[3 * gp + 0];   // (x_e, y_e)
            const float2 v1 = f2[3 * gp + 1];   // (z_e, x_o)
            const float2 v2 = f2[3 * gp + 2];   // (y_o, z_o)
            lx[p] = pkrtz_u(v0.x, v1.y);
            ly[p] = pkrtz_u(v0.y, v2.x);
            lz[p] = pkrtz_u(v1.x, v2.y);
        }
        __syncthreads();

        // ---- scan: wave c owns pairs [c*WPP, c*WPP+WPP) of this phase ----
        int cnt = 0;
        const int l = h * WAVES + c;   // list id, ascending j across l
        for (int r = 0; r < WPP / 64 && cnt < KNN; ++r) {
            const int pbase = c * WPP + r * 64;
            unsigned m[4] = {0u, 0u, 0u, 0u};
#pragma unroll
            for (int g4 = 0; g4 < 4; ++g4) {
#pragma unroll
                for (int w = 0; w < 4; ++w) {
                    const int pb = pbase + w * 16 + g4 * 4;
                    const uint4 X = *(const uint4*)&lx[pb];  // broadcast b128
                    const uint4 Y = *(const uint4*)&ly[pb];
                    const uint4 Z = *(const uint4*)&lz[pb];
                    bq_pair(X.x, Y.x, Z.x, qpx, qpy, qpz, r2, m[w]);
                    bq_pair(X.y, Y.y, Z.y, qpx, qpy, qpz, r2, m[w]);
                    bq_pair(X.z, Y.z, Z.z, qpx, qpy, qpz, r2, m[w]);
                    bq_pair(X.w, Y.w, Z.w, qpx, qpy, qpz, r2, m[w]);
                }
            }
            if (!(m[0] | m[1] | m[2] | m[3])) continue;

            // bit n of ev/od = pair (pbase+n) even/odd candidate
            unsigned long long ev =
                  (unsigned long long)(m[0] & 0xFFFFu)
                | ((unsigned long long)(m[1] & 0xFFFFu) << 16)
                | ((unsigned long long)(m[2] & 0xFFFFu) << 32)
                | ((unsigned long long)(m[3] & 0xFFFFu) << 48);
            unsigned long long od =
                  (unsigned long long)(m[0] >> 16)
                | ((unsigned long long)(m[1] >> 16) << 16)
                | ((unsigned long long)(m[2] >> 16) << 32)
                | ((unsigned long long)(m[3] >> 16) << 48);

            const int jb = h * (2 * PH_PAIRS) + 2 * pbase;
            while ((ev | od) && cnt < KNN) {
                const int pe = ev ? __builtin_ctzll(ev) : 127;
                const int po = od ? __builtin_ctzll(od) : 127;
                int j;
                if (pe <= po) { j = jb + 2 * pe;     ev &= ev - 1; }
                else          { j = jb + 2 * po + 1; od &= od - 1; }
                s_idx[q][l * KNN + cnt] = (unsigned short)j;
                ++cnt;
            }
        }
        s_cnt[q][l] = (unsigned char)cnt;
    }
    __syncthreads();

    // ---- merge (wave 0, lane = query): first 16 across 16 ordered lists ----
    if (c == 0) {
        int tot = 0;
        for (int l2 = 0; l2 < 16 && tot < KNN; ++l2) {
            const int f = s_cnt[q][l2];
            const int take = f < (KNN - tot) ? f : (KNN - tot);
            for (int t = 0; t < take; ++t)
                s_mrg[q][tot++] = s_idx[q][l2 * KNN + t];
        }
        // pad with first neighbor (self always in-ball: exact f16 zero dist)
        const unsigned short j0 = s_mrg[q][0];
        for (int t = tot; t < KNN; ++t) s_mrg[q][t] = j0;
    }
    __syncthreads();

    // ---- loss: 1024 (query, k-slot) items over 512 threads ----
    float sum = 0.0f;
#pragma unroll
    for (int kk = 0; kk < 2; ++kk) {
        const int k  = tid + kk * THREADS;
        const int qq = k >> 4;
        const int t  = k & 15;
        const int iq = (g & 127) * QPB + qq;
        const int j  = s_mrg[qq][t];
        sum += fabsf(flb[iq * 3 + 0] - flb[j * 3 + 0]) +
               fabsf(flb[iq * 3 + 1] - flb[j * 3 + 1]) +
               fabsf(flb[iq * 3 + 2] - flb[j * 3 + 2]);
    }
    for (int o = 32; o > 0; o >>= 1)
        sum += __shfl_down(sum, o, 64);
    if (q == 0) s_red[c] = sum;
    __syncthreads();
    if (tid == 0) {
        float t = 0.0f;
#pragma unroll
        for (int w = 0; w < WAVES; ++w) t += s_red[w];
        partial[g] = t;                // plain store, no atomics, no init
    }
}

__global__ __launch_bounds__(GROUPS)
void ballq_final(const float* __restrict__ partial, float* __restrict__ out)
{
    const int tid = threadIdx.x;       // 256
    float v = partial[tid];
    for (int o = 32; o > 0; o >>= 1)
        v += __shfl_down(v, o, 64);
    __shared__ float s[4];
    if ((tid & 63) == 0) s[tid >> 6] = v;
    __syncthreads();
    if (tid == 0)
        out[0] = (s[0] + s[1] + s[2] + s[3]) *
                 (1.0f / ((float)NB * NQ * KNN));
}

extern "C" void kernel_launch(void* const* d_in, const int* in_sizes, int n_in,
                              void* d_out, int out_size, void* d_ws, size_t ws_size,
                              hipStream_t stream)
{
    (void)in_sizes; (void)n_in; (void)out_size; (void)ws_size;
    const float* pc   = (const float*)d_in[0];
    const float* flow = (const float*)d_in[1];
    float* out     = (float*)d_out;
    float* partial = (float*)d_ws;     // 256 floats

    ballq_fused<<<GROUPS, THREADS, 0, stream>>>(pc, flow, partial);
    ballq_final<<<1, GROUPS, 0, stream>>>(partial, out);
}

// Round 12
// 36.838 us; speedup vs baseline: 1.7039x; 1.1719x over previous
//
#include <hip/hip_runtime.h>
#include <hip/hip_fp16.h>

// BallQLoss: B=2, N=8192, K=16, radius=0.5, L1 norm, mean over (B,N,K).
// v7: occupancy fix. K1 scan: 1024 blocks = 256 query-groups x 4 j-slices;
// block = 64 queries x 2048 candidates (1024 f16x2 pairs staged in LDS
// planes, ~30 KB total -> 4 blocks/CU = 8 waves/SIMD). Wave c scans 128
// pairs/2 rounds; packed v_pk f16 distance with -R^2 folded into the fma
// chain (9 VALU/pair); hit = sign bit merged into four independent mask
// chains; extraction in ascending j (pointnet2 first-K semantics).
// Per-slice first-16 lists (u16) + count bytes -> d_ws.
// K2 loss: 16 lanes/query, slice-decode, padded slots -> first neighbor;
// flow gather + L1; block partial -> plain store (no atomics, no init).
// K3: 1-block reduce of 1024 partials -> mean. Replay-safe throughout.

#define NQ   8192
#define NB   2
#define KNN  16
#define QPB  64
#define WAVES 8
#define THREADS (QPB * WAVES)          // 512
#define NBQ (NB * NQ)                  // 16384
#define GROUPS (NBQ / QPB)             // 256
#define SLICES 4
#define SL_PAIRS 1024                  // pairs per slice (2048 candidates)
#define WPP 128                        // pairs per wave (2 rounds of 64)
#define IDXROW 130                     // u16/row: 8 lists * 16 + 2 pad

static __device__ __forceinline__ unsigned pkrtz_u(float a, float b) {
    return __builtin_bit_cast(unsigned, __builtin_amdgcn_cvt_pkrtz(a, b));
}
static __device__ __forceinline__ __half2 u_as_h2(unsigned u) {
    return __builtin_bit_cast(__half2, u);
}
// one candidate PAIR: packed f16 (d2 - R^2) via fused fma chain; sign bits
// (bit15 = even cand, bit31 = odd cand) merged into mask chain mm.
static __device__ __forceinline__ void bq_pair(unsigned xu, unsigned yu,
                                               unsigned zu, __half2 qpx,
                                               __half2 qpy, __half2 qpz,
                                               __half2 nr2, unsigned& mm) {
    const __half2 dx = __hsub2(qpx, u_as_h2(xu));
    const __half2 dy = __hsub2(qpy, u_as_h2(yu));
    const __half2 dz = __hsub2(qpz, u_as_h2(zu));
    const __half2 t =
        __hfma2(dx, dx, __hfma2(dy, dy, __hfma2(dz, dz, nr2)));
    const unsigned su = __builtin_bit_cast(unsigned, t) & 0x80008000u;
    mm = su | (mm >> 1);
}

__global__ __launch_bounds__(THREADS, 8)
void ballq_scan(const float* __restrict__ pc,
                unsigned short* __restrict__ wsIdx,
                unsigned char* __restrict__ wsCnt)
{
    __shared__ __align__(16) unsigned lx[SL_PAIRS];   // 4 KB each
    __shared__ __align__(16) unsigned ly[SL_PAIRS];
    __shared__ __align__(16) unsigned lz[SL_PAIRS];
    __shared__ unsigned short s_idx[QPB][IDXROW];     // 16.6 KB
    __shared__ unsigned char  s_cnt[QPB][12];

    const int tid = threadIdx.x;
    const int q   = tid & 63;          // lane = query slot
    const int c   = tid >> 6;          // wave id
    const int s   = blockIdx.x & 3;    // j slice
    const int g   = blockIdx.x >> 2;   // query group 0..255
    const int b   = g >> 7;
    const int i   = (g & 127) * QPB + q;

    const float* __restrict__ pcb = pc + (size_t)b * NQ * 3;
    const float2* __restrict__ f2 = (const float2*)pcb;

    // ---- stage this slice's 1024 pairs into LDS planes (f16x2) ----
    for (int p = tid; p < SL_PAIRS; p += THREADS) {
        const int gp = s * SL_PAIRS + p;
        const float2 v0 = f2[3 * gp + 0];   // (x_e, y_e)
        const float2 v1 = f2[3 * gp + 1];   // (z_e, x_o)
        const float2 v2 = f2[3 * gp + 2];   // (y_o, z_o)
        lx[p] = pkrtz_u(v0.x, v1.y);
        ly[p] = pkrtz_u(v0.y, v2.x);
        lz[p] = pkrtz_u(v1.x, v2.y);
    }

    const float qx = pcb[i * 3 + 0];
    const float qy = pcb[i * 3 + 1];
    const float qz = pcb[i * 3 + 2];
    const __half2 qpx = u_as_h2(pkrtz_u(qx, qx));
    const __half2 qpy = u_as_h2(pkrtz_u(qy, qy));
    const __half2 qpz = u_as_h2(pkrtz_u(qz, qz));
    const __half2 nr2 = u_as_h2(0xB400B400u);   // (-0.25, -0.25)

    __syncthreads();

    // ---- scan: wave c owns pairs [c*WPP, c*WPP+WPP), 2 rounds of 64 ----
    int cnt = 0;
    for (int r = 0; r < WPP / 64 && cnt < KNN; ++r) {
        const int pbase = c * WPP + r * 64;
        unsigned m[4] = {0u, 0u, 0u, 0u};
#pragma unroll
        for (int g4 = 0; g4 < 4; ++g4) {
#pragma unroll
            for (int w = 0; w < 4; ++w) {
                const int pb = pbase + w * 16 + g4 * 4;
                const uint4 X = *(const uint4*)&lx[pb];  // broadcast b128
                const uint4 Y = *(const uint4*)&ly[pb];
                const uint4 Z = *(const uint4*)&lz[pb];
                bq_pair(X.x, Y.x, Z.x, qpx, qpy, qpz, nr2, m[w]);
                bq_pair(X.y, Y.y, Z.y, qpx, qpy, qpz, nr2, m[w]);
                bq_pair(X.z, Y.z, Z.z, qpx, qpy, qpz, nr2, m[w]);
                bq_pair(X.w, Y.w, Z.w, qpx, qpy, qpz, nr2, m[w]);
            }
        }
        // bit n of ev/od = pair (pbase+n) even/odd candidate
        unsigned long long ev =
              (unsigned long long)(m[0] & 0xFFFFu)
            | ((unsigned long long)(m[1] & 0xFFFFu) << 16)
            | ((unsigned long long)(m[2] & 0xFFFFu) << 32)
            | ((unsigned long long)(m[3] & 0xFFFFu) << 48);
        unsigned long long od =
              (unsigned long long)(m[0] >> 16)
            | ((unsigned long long)(m[1] >> 16) << 16)
            | ((unsigned long long)(m[2] >> 16) << 32)
            | ((unsigned long long)(m[3] >> 16) << 48);

        const int jb = s * (2 * SL_PAIRS) + 2 * pbase;
        while ((ev | od) && cnt < KNN) {
            const int pe = ev ? __builtin_ctzll(ev) : 127;
            const int po = od ? __builtin_ctzll(od) : 127;
            int j;
            if (pe <= po) { j = jb + 2 * pe;     ev &= ev - 1; }
            else          { j = jb + 2 * po + 1; od &= od - 1; }
            s_idx[q][c * KNN + cnt] = (unsigned short)j;
            ++cnt;
        }
    }
    s_cnt[q][c] = (unsigned char)cnt;
    __syncthreads();

    // ---- merge (wave 0, lane = query): first <=16 over this slice ----
    if (c == 0) {
        const int qid = g * QPB + q;   // 0..16383
        unsigned short* __restrict__ rp =
            wsIdx + ((size_t)s * NBQ + qid) * KNN;
        int outc = 0;
        for (int c2 = 0; c2 < WAVES && outc < KNN; ++c2) {
            const int f = s_cnt[q][c2];
            const int take = f < (KNN - outc) ? f : (KNN - outc);
            for (int t = 0; t < take; ++t)
                rp[outc++] = s_idx[q][c2 * KNN + t];
        }
        wsCnt[qid * 4 + s] = (unsigned char)outc;
    }
}

__global__ __launch_bounds__(256)
void ballq_loss(const float* __restrict__ flow,
                const unsigned short* __restrict__ wsIdx,
                const unsigned char* __restrict__ wsCnt,
                float* __restrict__ partial)
{
    const int tid = blockIdx.x * 256 + threadIdx.x;
    const int qid = tid >> 4;          // one query per 16 lanes
    const int t   = tid & 15;          // k-slot
    const int b   = qid >> 13;
    const int iq  = qid & (NQ - 1);
    const float* __restrict__ flb = flow + (size_t)b * NQ * 3;

    const unsigned cw = *(const unsigned*)(wsCnt + qid * 4);
    const int b0 = cw & 0xFF;
    const int b1 = (cw >> 8)  & 0xFF;
    const int b2 = (cw >> 16) & 0xFF;
    const int c1 = b0, c2c = b0 + b1, c3 = b0 + b1 + b2;
    int tot = c3 + ((cw >> 24) & 0xFF);
    if (tot > KNN) tot = KNN;
    // tot >= 1 always: self is in-ball (exact f16 zero distance)

    const int seff = (t < tot) ? t : 0;   // padded slots -> first neighbor
    const int sl   = (seff >= c1) + (seff >= c2c) + (seff >= c3);
    const int cum  = (sl == 0) ? 0 : (sl == 1) ? c1 : (sl == 2) ? c2c : c3;
    const int j    = wsIdx[((size_t)sl * NBQ + qid) * KNN + (seff - cum)];

    const float fx = flb[iq * 3 + 0];
    const float fy = flb[iq * 3 + 1];
    const float fz = flb[iq * 3 + 2];
    float l = fabsf(fx - flb[j * 3 + 0]) +
              fabsf(fy - flb[j * 3 + 1]) +
              fabsf(fz - flb[j * 3 + 2]);

    for (int o = 32; o > 0; o >>= 1)
        l += __shfl_down(l, o, 64);
    __shared__ float sred[4];
    if ((threadIdx.x & 63) == 0) sred[threadIdx.x >> 6] = l;
    __syncthreads();
    if (threadIdx.x == 0)
        partial[blockIdx.x] = sred[0] + sred[1] + sred[2] + sred[3];
}

__global__ __launch_bounds__(1024)
void ballq_final(const float* __restrict__ partial, float* __restrict__ out)
{
    const int tid = threadIdx.x;       // 1024 threads, 16 waves
    float v = partial[tid];
    for (int o = 32; o > 0; o >>= 1)
        v += __shfl_down(v, o, 64);
    __shared__ float s[16];
    if ((tid & 63) == 0) s[tid >> 6] = v;
    __syncthreads();
    if (tid == 0) {
        float t = 0.0f;
#pragma unroll
        for (int w = 0; w < 16; ++w) t += s[w];
        out[0] = t * (1.0f / ((float)NB * NQ * KNN));
    }
}

extern "C" void kernel_launch(void* const* d_in, const int* in_sizes, int n_in,
                              void* d_out, int out_size, void* d_ws, size_t ws_size,
                              hipStream_t stream)
{
    (void)in_sizes; (void)n_in; (void)out_size; (void)ws_size;
    const float* pc   = (const float*)d_in[0];
    const float* flow = (const float*)d_in[1];
    float* out = (float*)d_out;

    // ws layout: idx lists (4 slices x 16384 q x 16 u16 = 2 MB),
    //            counts (16384 x 4 B), partials (1024 f32)
    unsigned short* wsIdx = (unsigned short*)d_ws;
    unsigned char*  wsCnt = (unsigned char*)d_ws + (size_t)SLICES * NBQ * KNN * 2;
    float* partial = (float*)(wsCnt + (size_t)NBQ * 4);

    ballq_scan<<<GROUPS * SLICES, THREADS, 0, stream>>>(pc, wsIdx, wsCnt);
    ballq_loss<<<NBQ * 16 / 256, 256, 0, stream>>>(flow, wsIdx, wsCnt, partial);
    ballq_final<<<1, 1024, 0, stream>>>(partial, out);
}